// Round 5
// baseline (572.581 us; speedup 1.0000x reference)
//
#include <hip/hip_runtime.h>
#include <cstdint>
#include <cstddef>

// Problem constants (fixed by the reference)
#define N_NODES 10000
#define F_IN    512
#define NHID    32
#define LATENT  16

// native vector type (accepted by __builtin_nontemporal_store; HIP's float4
// is a class and gets rejected)
typedef float v4f __attribute__((ext_vector_type(4)));

// ---------------------------------------------------------------------------
// Algebraic identity: no nonlinearity between the two GCN layers, so
//   z = A @ ((A @ (x@W1)) @ W2) = A @ (A @ (x @ (W1@W2))).
// W12 = W1@W2 (512x16) is precomputed; both SpMMs run at D=16.
// ---------------------------------------------------------------------------

// W12[r][c] = sum_k W1[r][k] * W2[k][c];  512x32 @ 32x16 -> 512x16.
__global__ __launch_bounds__(256) void w12_kernel(const float* __restrict__ W1,
                                                  const float* __restrict__ W2,
                                                  float* __restrict__ W12) {
    __shared__ float w2s[NHID * LATENT];
    for (int t = threadIdx.x; t < NHID * LATENT; t += 256) w2s[t] = W2[t];
    __syncthreads();

    const int idx = blockIdx.x * 256 + threadIdx.x;  // 32 blocks * 256 = 8192
    const int r = idx >> 4;            // / LATENT
    const int c = idx & (LATENT - 1);  // % LATENT
    float acc = 0.f;
#pragma unroll
    for (int k = 0; k < NHID; ++k) acc += W1[r * NHID + k] * w2s[k * LATENT + c];
    W12[idx] = acc;  // idx == r*LATENT + c (row-major)
}

// ---------------------------------------------------------------------------
// GEMM1: g0 = x @ W12   [10000,512] x [512,16] -> [10000,16]
// block = 256 threads = 16 rows x 16 cols; x rows staged in LDS (32 KB) via
// float4 (dwordx4) loads. Also zero-initializes both atomic accumulators
// (g1, z: 160k floats each) -- grid is exactly 160k threads.
// ---------------------------------------------------------------------------
__global__ __launch_bounds__(256) void gemm1_kernel(const float* __restrict__ x,
                                                    const float* __restrict__ W12,
                                                    float* __restrict__ g0,
                                                    float* __restrict__ g1,
                                                    float* __restrict__ z) {
    const int gid = blockIdx.x * 256 + threadIdx.x;  // 625*256 = 160000 exactly
    g1[gid] = 0.f;   // zero layer-1 accumulator (N*16 floats)
    z[gid]  = 0.f;   // zero layer-2 accumulator (N*16 floats)

    __shared__ float xs[16][F_IN];  // 32 KB
    const int row0 = blockIdx.x * 16;  // 625 blocks x 16 rows = 10000 exactly
    {
        // vectorized cooperative staging: 16*128 float4 = 8 iters/thread
        const float4* __restrict__ xg = (const float4*)(x + (size_t)row0 * F_IN);
        float4* __restrict__ xsv = (float4*)&xs[0][0];
#pragma unroll
        for (int t = threadIdx.x; t < 16 * (F_IN / 4); t += 256) {
            xsv[t] = xg[t];
        }
    }
    __syncthreads();

    const int col = threadIdx.x & 15;
    const int r   = threadIdx.x >> 4;
    float a0 = 0.f, a1 = 0.f, a2 = 0.f, a3 = 0.f;
#pragma unroll 4
    for (int k = 0; k < F_IN; k += 4) {
        const float4 xv = *(const float4*)&xs[r][k];  // ds_read_b128, broadcast
        a0 += xv.x * W12[(k + 0) * LATENT + col];
        a1 += xv.y * W12[(k + 1) * LATENT + col];
        a2 += xv.z * W12[(k + 2) * LATENT + col];
        a3 += xv.w * W12[(k + 3) * LATENT + col];
    }
    g0[(size_t)(row0 + r) * LATENT + col] = (a0 + a1) + (a2 + a3);
}

// ---------------------------------------------------------------------------
// SpMM (scatter form): hout[dst[e]][d] += w[e] * hin[src[e]][d],  D = 16.
// Thread per (edge, feature-QUAD): one float4 gather + 4 atomics per thread.
// vs the per-(edge,feature) map: edge metadata loaded once per 4 features
// and the gather is a single dwordx4 -> ~2.7x fewer issued instructions per
// atomic. Atomic count unchanged (E*16 per layer).
// ---------------------------------------------------------------------------
__global__ __launch_bounds__(256) void spmm16_kernel(const int* __restrict__ src,
                                                     const int* __restrict__ dst,
                                                     const float* __restrict__ w,
                                                     const float* __restrict__ hin,
                                                     float* __restrict__ hout,
                                                     int E) {
    const int idx = blockIdx.x * 256 + threadIdx.x;
    const int e = idx >> 2;        // 4 quads per edge
    const int q = idx & 3;         // which float4 of the 16 features
    if (e < E) {
        const int s = src[e];
        const int t = dst[e];
        const float we = w[e];
        const float4 hv = ((const float4*)(hin + (size_t)s * LATENT))[q];
        float* __restrict__ hp = hout + (size_t)t * LATENT + q * 4;
        atomicAdd(&hp[0], we * hv.x);
        atomicAdd(&hp[1], we * hv.y);
        atomicAdd(&hp[2], we * hv.z);
        atomicAdd(&hp[3], we * hv.w);
    }
}

// ---------------------------------------------------------------------------
// Decoder: out[i][j] = sigmoid(dot(z[i], z[j])), N x N output.
// Each thread owns FOUR consecutive columns j0..j0+3 (4x float4 of z in
// VGPRs) and stores one nontemporal dwordx4 per row; z[i] loads are
// block-uniform -> scalarized. Write-BW bound: 400 MB (~63 us floor).
// ---------------------------------------------------------------------------
#define TI 32

__device__ __forceinline__ float sigmoid_fast(float x) {
    return __builtin_amdgcn_rcpf(1.0f + __expf(-x));
}

__global__ __launch_bounds__(256) void decoder_kernel(const float* __restrict__ z,
                                                      float* __restrict__ out) {
    const int j0 = (blockIdx.x * 256 + threadIdx.x) << 2;  // 4 cols per thread
    const int i0 = blockIdx.y * TI;
    if (j0 >= N_NODES) return;   // N_NODES % 4 == 0, so j0..j0+3 all valid

    // 4 column vectors z[j0+q][0..15] in registers (fully unrolled -> static idx)
    float4 zj0[4], zj1[4], zj2[4], zj3[4];
    {
        const float4* zp0 = (const float4*)(z + (size_t)(j0 + 0) * LATENT);
        const float4* zp1 = (const float4*)(z + (size_t)(j0 + 1) * LATENT);
        const float4* zp2 = (const float4*)(z + (size_t)(j0 + 2) * LATENT);
        const float4* zp3 = (const float4*)(z + (size_t)(j0 + 3) * LATENT);
#pragma unroll
        for (int p = 0; p < 4; ++p) {
            zj0[p] = zp0[p]; zj1[p] = zp1[p]; zj2[p] = zp2[p]; zj3[p] = zp3[p];
        }
    }

    const int imax = min(TI, N_NODES - i0);
#pragma unroll 2
    for (int ii = 0; ii < imax; ++ii) {
        const float4* __restrict__ zi = (const float4*)(z + (size_t)(i0 + ii) * LATENT);
        const float4 a0 = zi[0], a1 = zi[1], a2 = zi[2], a3 = zi[3];  // s_loads

        v4f r;
        r.x = a0.x*zj0[0].x + a0.y*zj0[0].y + a0.z*zj0[0].z + a0.w*zj0[0].w
            + a1.x*zj0[1].x + a1.y*zj0[1].y + a1.z*zj0[1].z + a1.w*zj0[1].w
            + a2.x*zj0[2].x + a2.y*zj0[2].y + a2.z*zj0[2].z + a2.w*zj0[2].w
            + a3.x*zj0[3].x + a3.y*zj0[3].y + a3.z*zj0[3].z + a3.w*zj0[3].w;
        r.y = a0.x*zj1[0].x + a0.y*zj1[0].y + a0.z*zj1[0].z + a0.w*zj1[0].w
            + a1.x*zj1[1].x + a1.y*zj1[1].y + a1.z*zj1[1].z + a1.w*zj1[1].w
            + a2.x*zj1[2].x + a2.y*zj1[2].y + a2.z*zj1[2].z + a2.w*zj1[2].w
            + a3.x*zj1[3].x + a3.y*zj1[3].y + a3.z*zj1[3].z + a3.w*zj1[3].w;
        r.z = a0.x*zj2[0].x + a0.y*zj2[0].y + a0.z*zj2[0].z + a0.w*zj2[0].w
            + a1.x*zj2[1].x + a1.y*zj2[1].y + a1.z*zj2[1].z + a1.w*zj2[1].w
            + a2.x*zj2[2].x + a2.y*zj2[2].y + a2.z*zj2[2].z + a2.w*zj2[2].w
            + a3.x*zj2[3].x + a3.y*zj2[3].y + a3.z*zj2[3].z + a3.w*zj2[3].w;
        r.w = a0.x*zj3[0].x + a0.y*zj3[0].y + a0.z*zj3[0].z + a0.w*zj3[0].w
            + a1.x*zj3[1].x + a1.y*zj3[1].y + a1.z*zj3[1].z + a1.w*zj3[1].w
            + a2.x*zj3[2].x + a2.y*zj3[2].y + a2.z*zj3[2].z + a2.w*zj3[2].w
            + a3.x*zj3[3].x + a3.y*zj3[3].y + a3.z*zj3[3].z + a3.w*zj3[3].w;

        r.x = sigmoid_fast(r.x);
        r.y = sigmoid_fast(r.y);
        r.z = sigmoid_fast(r.z);
        r.w = sigmoid_fast(r.w);

        __builtin_nontemporal_store(
            r, (v4f*)(out + (size_t)(i0 + ii) * N_NODES + j0));
    }
}

// ---------------------------------------------------------------------------
// Launch: scratch (g0, g1, W12) lives inside the adj-recon region of d_out,
// which the decoder fully overwrites last. z accumulates directly into its
// final spot (tail of d_out). 5 dispatches total.
// ---------------------------------------------------------------------------
extern "C" void kernel_launch(void* const* d_in, const int* in_sizes, int n_in,
                              void* d_out, int out_size, void* d_ws, size_t ws_size,
                              hipStream_t stream) {
    const float* x  = (const float*)d_in[0];   // [N, 512]
    const float* W1 = (const float*)d_in[1];   // [512, 32]
    const float* W2 = (const float*)d_in[2];   // [32, 16]
    const int*   ei = (const int*)d_in[3];     // [2, E]
    const float* ew = (const float*)d_in[4];   // [E]
    const int E = in_sizes[3] / 2;
    const int* src = ei;
    const int* dst = ei + E;

    float* out = (float*)d_out;                              // [N, N]
    float* z   = out + (size_t)N_NODES * N_NODES;            // [N, 16] (final tail)

    // scratch inside the adj region (overwritten by decoder at the end)
    float* g0  = out;                          // N*16 floats @ 0
    float* g1  = g0 + N_NODES * LATENT;        // N*16 floats @ 160000
    float* W12 = g1 + N_NODES * LATENT;        // 512*16 floats @ 320000

    // fold weights: W12 = W1 @ W2
    w12_kernel<<<(F_IN * LATENT) / 256, 256, 0, stream>>>(W1, W2, W12);

    // g0 = x @ W12 (also zeroes g1 and z)
    gemm1_kernel<<<N_NODES / 16, 256, 0, stream>>>(x, W12, g0, g1, z);

    // g1 = A @ g0 ; z = A @ g1   (both at D=16, thread per edge-quad)
    spmm16_kernel<<<(E * 4 + 255) / 256, 256, 0, stream>>>(src, dst, ew, g0, g1, E);
    spmm16_kernel<<<(E * 4 + 255) / 256, 256, 0, stream>>>(src, dst, ew, g1, z, E);

    // decoder: adj_recon = sigmoid(z @ z^T)
    dim3 dgrid((N_NODES / 4 + 255) / 256, (N_NODES + TI - 1) / TI);
    decoder_kernel<<<dgrid, 256, 0, stream>>>(z, out);
}

// Round 6
// 475.597 us; speedup vs baseline: 1.2039x; 1.2039x over previous
//
#include <hip/hip_runtime.h>
#include <cstdint>
#include <cstddef>

// Problem constants (fixed by the reference)
#define N_NODES 10000
#define F_IN    512
#define NHID    32
#define LATENT  16

// native vector type (accepted by __builtin_nontemporal_store; HIP's float4
// is a class and gets rejected)
typedef float v4f __attribute__((ext_vector_type(4)));

// ---------------------------------------------------------------------------
// Algebraic identity: no nonlinearity between the two GCN layers, so
//   z = A @ ((A @ (x@W1)) @ W2) = A @ (A @ (x @ (W1@W2))).
// W12 = W1@W2 (512x16) is precomputed; both SpMMs run at D=16.
// ---------------------------------------------------------------------------

// W12[r][c] = sum_k W1[r][k] * W2[k][c];  512x32 @ 32x16 -> 512x16.
__global__ __launch_bounds__(256) void w12_kernel(const float* __restrict__ W1,
                                                  const float* __restrict__ W2,
                                                  float* __restrict__ W12) {
    __shared__ float w2s[NHID * LATENT];
    for (int t = threadIdx.x; t < NHID * LATENT; t += 256) w2s[t] = W2[t];
    __syncthreads();

    const int idx = blockIdx.x * 256 + threadIdx.x;  // 32 blocks * 256 = 8192
    const int r = idx >> 4;            // / LATENT
    const int c = idx & (LATENT - 1);  // % LATENT
    float acc = 0.f;
#pragma unroll
    for (int k = 0; k < NHID; ++k) acc += W1[r * NHID + k] * w2s[k * LATENT + c];
    W12[idx] = acc;  // idx == r*LATENT + c (row-major)
}

// ---------------------------------------------------------------------------
// GEMM1: g0 = x @ W12   [10000,512] x [512,16] -> [10000,16]
// block = 256 threads = 16 rows x 16 cols; x rows staged in LDS (32 KB) via
// float4 (dwordx4) loads. Also zero-initializes both atomic accumulators
// (g1, z: 160k floats each) -- grid is exactly 160k threads.
// ---------------------------------------------------------------------------
__global__ __launch_bounds__(256) void gemm1_kernel(const float* __restrict__ x,
                                                    const float* __restrict__ W12,
                                                    float* __restrict__ g0,
                                                    float* __restrict__ g1,
                                                    float* __restrict__ z) {
    const int gid = blockIdx.x * 256 + threadIdx.x;  // 625*256 = 160000 exactly
    g1[gid] = 0.f;   // zero layer-1 accumulator (N*16 floats)
    z[gid]  = 0.f;   // zero layer-2 accumulator (N*16 floats)

    __shared__ float xs[16][F_IN];  // 32 KB
    const int row0 = blockIdx.x * 16;  // 625 blocks x 16 rows = 10000 exactly
    {
        // vectorized cooperative staging: 16*128 float4 = 8 iters/thread
        const float4* __restrict__ xg = (const float4*)(x + (size_t)row0 * F_IN);
        float4* __restrict__ xsv = (float4*)&xs[0][0];
#pragma unroll
        for (int t = threadIdx.x; t < 16 * (F_IN / 4); t += 256) {
            xsv[t] = xg[t];
        }
    }
    __syncthreads();

    const int col = threadIdx.x & 15;
    const int r   = threadIdx.x >> 4;
    float a0 = 0.f, a1 = 0.f, a2 = 0.f, a3 = 0.f;
#pragma unroll 4
    for (int k = 0; k < F_IN; k += 4) {
        const float4 xv = *(const float4*)&xs[r][k];  // ds_read_b128, broadcast
        a0 += xv.x * W12[(k + 0) * LATENT + col];
        a1 += xv.y * W12[(k + 1) * LATENT + col];
        a2 += xv.z * W12[(k + 2) * LATENT + col];
        a3 += xv.w * W12[(k + 3) * LATENT + col];
    }
    g0[(size_t)(row0 + r) * LATENT + col] = (a0 + a1) + (a2 + a3);
}

// ---------------------------------------------------------------------------
// SpMM (scatter form): hout[dst[e]][d] += w[e] * hin[src[e]][d],  D = 16.
// Thread per (edge, feature) -- the measured-best map: one atomic
// instruction's 64 lanes cover 4 edges x 16 features = 4 COMPLETE 64B lines
// -> 1 L2 line-RMW transaction per edge. (R5's quad map generated 4 partial
// line transactions per edge and ran ~4x slower -- do not regress this.)
// Grid-stride at 2048 blocks so iterations pipeline the loads (ILP + TLP).
// ---------------------------------------------------------------------------
__global__ __launch_bounds__(256) void spmm16_kernel(const int* __restrict__ src,
                                                     const int* __restrict__ dst,
                                                     const float* __restrict__ w,
                                                     const float* __restrict__ hin,
                                                     float* __restrict__ hout,
                                                     int E) {
    const int total  = E * LATENT;
    const int stride = gridDim.x * 256;
    for (int idx = blockIdx.x * 256 + threadIdx.x; idx < total; idx += stride) {
        const int e = idx >> 4;            // / LATENT
        const int d = idx & (LATENT - 1);  // % LATENT
        const float val = w[e] * hin[((size_t)src[e] << 4) + d];
        atomicAdd(&hout[((size_t)dst[e] << 4) + d], val);
    }
}

// ---------------------------------------------------------------------------
// Decoder: out[i][j] = sigmoid(dot(z[i], z[j])), N x N output.
// Each thread owns FOUR consecutive columns j0..j0+3 (4x float4 of z in
// VGPRs) and stores one nontemporal dwordx4 per row; z[i] loads are
// block-uniform -> scalarized. Write-BW bound: 400 MB (~63 us floor).
// ---------------------------------------------------------------------------
#define TI 32

__device__ __forceinline__ float sigmoid_fast(float x) {
    return __builtin_amdgcn_rcpf(1.0f + __expf(-x));
}

__global__ __launch_bounds__(256) void decoder_kernel(const float* __restrict__ z,
                                                      float* __restrict__ out) {
    const int j0 = (blockIdx.x * 256 + threadIdx.x) << 2;  // 4 cols per thread
    const int i0 = blockIdx.y * TI;
    if (j0 >= N_NODES) return;   // N_NODES % 4 == 0, so j0..j0+3 all valid

    // 4 column vectors z[j0+q][0..15] in registers (fully unrolled -> static idx)
    float4 zj0[4], zj1[4], zj2[4], zj3[4];
    {
        const float4* zp0 = (const float4*)(z + (size_t)(j0 + 0) * LATENT);
        const float4* zp1 = (const float4*)(z + (size_t)(j0 + 1) * LATENT);
        const float4* zp2 = (const float4*)(z + (size_t)(j0 + 2) * LATENT);
        const float4* zp3 = (const float4*)(z + (size_t)(j0 + 3) * LATENT);
#pragma unroll
        for (int p = 0; p < 4; ++p) {
            zj0[p] = zp0[p]; zj1[p] = zp1[p]; zj2[p] = zp2[p]; zj3[p] = zp3[p];
        }
    }

    const int imax = min(TI, N_NODES - i0);
#pragma unroll 2
    for (int ii = 0; ii < imax; ++ii) {
        const float4* __restrict__ zi = (const float4*)(z + (size_t)(i0 + ii) * LATENT);
        const float4 a0 = zi[0], a1 = zi[1], a2 = zi[2], a3 = zi[3];  // s_loads

        v4f r;
        r.x = a0.x*zj0[0].x + a0.y*zj0[0].y + a0.z*zj0[0].z + a0.w*zj0[0].w
            + a1.x*zj0[1].x + a1.y*zj0[1].y + a1.z*zj0[1].z + a1.w*zj0[1].w
            + a2.x*zj0[2].x + a2.y*zj0[2].y + a2.z*zj0[2].z + a2.w*zj0[2].w
            + a3.x*zj0[3].x + a3.y*zj0[3].y + a3.z*zj0[3].z + a3.w*zj0[3].w;
        r.y = a0.x*zj1[0].x + a0.y*zj1[0].y + a0.z*zj1[0].z + a0.w*zj1[0].w
            + a1.x*zj1[1].x + a1.y*zj1[1].y + a1.z*zj1[1].z + a1.w*zj1[1].w
            + a2.x*zj1[2].x + a2.y*zj1[2].y + a2.z*zj1[2].z + a2.w*zj1[2].w
            + a3.x*zj1[3].x + a3.y*zj1[3].y + a3.z*zj1[3].z + a3.w*zj1[3].w;
        r.z = a0.x*zj2[0].x + a0.y*zj2[0].y + a0.z*zj2[0].z + a0.w*zj2[0].w
            + a1.x*zj2[1].x + a1.y*zj2[1].y + a1.z*zj2[1].z + a1.w*zj2[1].w
            + a2.x*zj2[2].x + a2.y*zj2[2].y + a2.z*zj2[2].z + a2.w*zj2[2].w
            + a3.x*zj2[3].x + a3.y*zj2[3].y + a3.z*zj2[3].z + a3.w*zj2[3].w;
        r.w = a0.x*zj3[0].x + a0.y*zj3[0].y + a0.z*zj3[0].z + a0.w*zj3[0].w
            + a1.x*zj3[1].x + a1.y*zj3[1].y + a1.z*zj3[1].z + a1.w*zj3[1].w
            + a2.x*zj3[2].x + a2.y*zj3[2].y + a2.z*zj3[2].z + a2.w*zj3[2].w
            + a3.x*zj3[3].x + a3.y*zj3[3].y + a3.z*zj3[3].z + a3.w*zj3[3].w;

        r.x = sigmoid_fast(r.x);
        r.y = sigmoid_fast(r.y);
        r.z = sigmoid_fast(r.z);
        r.w = sigmoid_fast(r.w);

        __builtin_nontemporal_store(
            r, (v4f*)(out + (size_t)(i0 + ii) * N_NODES + j0));
    }
}

// ---------------------------------------------------------------------------
// Launch: scratch (g0, g1, W12) lives inside the adj-recon region of d_out,
// which the decoder fully overwrites last. z accumulates directly into its
// final spot (tail of d_out). 5 dispatches total.
// ---------------------------------------------------------------------------
extern "C" void kernel_launch(void* const* d_in, const int* in_sizes, int n_in,
                              void* d_out, int out_size, void* d_ws, size_t ws_size,
                              hipStream_t stream) {
    const float* x  = (const float*)d_in[0];   // [N, 512]
    const float* W1 = (const float*)d_in[1];   // [512, 32]
    const float* W2 = (const float*)d_in[2];   // [32, 16]
    const int*   ei = (const int*)d_in[3];     // [2, E]
    const float* ew = (const float*)d_in[4];   // [E]
    const int E = in_sizes[3] / 2;
    const int* src = ei;
    const int* dst = ei + E;

    float* out = (float*)d_out;                              // [N, N]
    float* z   = out + (size_t)N_NODES * N_NODES;            // [N, 16] (final tail)

    // scratch inside the adj region (overwritten by decoder at the end)
    float* g0  = out;                          // N*16 floats @ 0
    float* g1  = g0 + N_NODES * LATENT;        // N*16 floats @ 160000
    float* W12 = g1 + N_NODES * LATENT;        // 512*16 floats @ 320000

    // fold weights: W12 = W1 @ W2
    w12_kernel<<<(F_IN * LATENT) / 256, 256, 0, stream>>>(W1, W2, W12);

    // g0 = x @ W12 (also zeroes g1 and z)
    gemm1_kernel<<<N_NODES / 16, 256, 0, stream>>>(x, W12, g0, g1, z);

    // g1 = A @ g0 ; z = A @ g1   (both at D=16, thread per (edge,feature),
    // grid-stride at 2048 blocks)
    spmm16_kernel<<<2048, 256, 0, stream>>>(src, dst, ew, g0, g1, E);
    spmm16_kernel<<<2048, 256, 0, stream>>>(src, dst, ew, g1, z, E);

    // decoder: adj_recon = sigmoid(z @ z^T)
    dim3 dgrid((N_NODES / 4 + 255) / 256, (N_NODES + TI - 1) / TI);
    decoder_kernel<<<dgrid, 256, 0, stream>>>(z, out);
}